// Round 17
// baseline (644.052 us; speedup 1.0000x reference)
//
#include <hip/hip_runtime.h>
#include <hip/hip_fp16.h>

// ---------------------------------------------------------------------------
// MLPForwardPolicy — r16 champion + depth-3 W ring (stall-free DMA lead).
//
// r16 model: time ≈ staged-bytes @ ~6.4 TB/s + per-step vmcnt stall. Depth-2
// ring gives W(t) only ~1-step (~500cy) lead vs ~900cy HBM latency -> ~400cy
// stall/step. r17: W ring depth 3 (3x16KB LDS slots, still 3 blocks/CU),
// A direct global->VGPR depth 2 (L2-resident, ~200-400cy latency; r12-proven
// pattern). Ledger (issue [A(t+2), W(t+3)] per step): vmcnt(12) steady,
// 8 @ ns-2, 0 @ ns-1. Barriers unchanged; slot(t+3)==slot(t) guarded by the
// post-compute barrier. f16 split-K partials retained.
// Ranking: r16=561 r11=592 r7=606 r10/r15=656 r3=663 r6=669 r8=686 r9=694.
// ---------------------------------------------------------------------------

typedef _Float16 f16;
typedef _Float16 f16x4 __attribute__((ext_vector_type(4)));
typedef _Float16 f16x8 __attribute__((ext_vector_type(8)));
typedef float f32x4 __attribute__((ext_vector_type(4)));

#define DH 9216
#define SPLIT 8960

__device__ __forceinline__ void gload16(const void* g, void* l) {
    __builtin_amdgcn_global_load_lds(
        (const __attribute__((address_space(1))) void*)g,
        (__attribute__((address_space(3))) void*)l, 16, 0, 0);
}

// ---------------- f32 -> f16 ----------------
__global__ void cvt_kernel(const float* __restrict__ in, f16* __restrict__ out, int n) {
    for (int i = (blockIdx.x * blockDim.x + threadIdx.x) * 4; i < n;
         i += gridDim.x * blockDim.x * 4) {
        float4 v = *(const float4*)(in + i);
        f16x4 h = {(_Float16)v.x, (_Float16)v.y, (_Float16)v.z, (_Float16)v.w};
        *(f16x4*)(out + i) = h;
    }
}

// ---------------- streaming GEMM: P[y] = A[128-row][Kh] @ W[Kh, 128-col] ----
// linear grid (2*72)<<yshift blocks of 256 threads; y = bid & (S-1)
// rem = bid >> yshift: m0 = (rem&1)*128, n0 = (rem>>1)*128
// 4 waves 2x2: wave(wm,wn) owns rows m0+wm*64..+64 x cols n0+wn*64..+64
__global__ __launch_bounds__(256, 3) void gemm_kernel(
    const f16* __restrict__ A, int K, int Kh, int yshift,
    const float* __restrict__ W,
    f16* __restrict__ P)   // [S][256][9216] f16 partials
{
    __shared__ __align__(16) char lds[3][16384];   // W f32 ring, depth 3
    const int bid  = blockIdx.x;
    const int y    = bid & ((1 << yshift) - 1);
    const int rem  = bid >> yshift;
    const int m0   = (rem & 1) << 7;
    const int n0   = (rem >> 1) << 7;
    const int tid  = threadIdx.x;
    const int lane = tid & 63;
    const int wid  = tid >> 6;
    const int wm   = wid >> 1, wn = wid & 1;
    const int kbase = y * Kh;
    const int ns   = Kh >> 5;                     // BK = 32 (64 or 36)

    f32x4 acc[4][4] = {};
    f16x8 aE[4], aO[4];

    // ---- hoisted W DMA source pointers (advance one stage per issue) ----
    // granule g = tid + r*256 (1024): k = g>>5, p = g&31,
    // src col-group cg = p ^ ((5*(k>>3)) & 31)
    const float* wsrc0;
    const float* wsrc1;
    const float* wsrc2;
    const float* wsrc3;
    {
        int g0 = tid,      k0 = g0 >> 5, c0 = (g0 & 31) ^ ((5 * (k0 >> 3)) & 31);
        int g1 = tid + 256, k1 = g1 >> 5, c1 = (g1 & 31) ^ ((5 * (k1 >> 3)) & 31);
        int g2 = tid + 512, k2 = g2 >> 5, c2 = (g2 & 31) ^ ((5 * (k2 >> 3)) & 31);
        int g3 = tid + 768, k3 = g3 >> 5, c3 = (g3 & 31) ^ ((5 * (k3 >> 3)) & 31);
        wsrc0 = W + (size_t)(kbase + k0) * DH + n0 + (c0 << 2);
        wsrc1 = W + (size_t)(kbase + k1) * DH + n0 + (c1 << 2);
        wsrc2 = W + (size_t)(kbase + k2) * DH + n0 + (c2 << 2);
        wsrc3 = W + (size_t)(kbase + k3) * DH + n0 + (c3 << 2);
    }
    const int q  = lane >> 4;
    const int lc = lane & 15;
    // A fragment base: row = m0 + wm*64 + lc (+ri*16), k = kbase + q*8 (+t*32)
    const f16* abase = A + (size_t)(m0 + wm * 64 + lc) * K + kbase + (q << 3);

    auto issueW = [&](char* dst) {        // 4 DMA instr; advance ptrs 1 stage
        gload16(wsrc0, dst + (size_t)tid * 16);          wsrc0 += 32 * DH;
        gload16(wsrc1, dst + (size_t)(tid + 256) * 16);  wsrc1 += 32 * DH;
        gload16(wsrc2, dst + (size_t)(tid + 512) * 16);  wsrc2 += 32 * DH;
        gload16(wsrc3, dst + (size_t)(tid + 768) * 16);  wsrc3 += 32 * DH;
    };
    auto loadA = [&](f16x8* a, int t) {   // 4 x 16B direct to VGPR (r12-proven)
        const f16* p = abase + (t << 5);
#pragma unroll
        for (int ri = 0; ri < 4; ++ri)
            a[ri] = *(const f16x8*)(p + (size_t)(ri << 4) * K);
    };
    auto step = [&](const char* wslotp, f16x8* a) {
        const float* wl = (const float*)wslotp;
        const int wbase = (q << 10) + (lc & 3);
        f16x8 bf[4];
#pragma unroll
        for (int ni = 0; ni < 4; ++ni) {
            int p = ((wn << 4) + (ni << 2) + (lc >> 2)) ^ (5 * q);
            int fi = wbase + ((p & 31) << 2);
            f16x8 b;
#pragma unroll
            for (int j = 0; j < 8; ++j)
                b[j] = (_Float16)wl[fi + (j << 7)];
            bf[ni] = b;
        }
#pragma unroll
        for (int ri = 0; ri < 4; ++ri)
#pragma unroll
            for (int ni = 0; ni < 4; ++ni)
                acc[ri][ni] = __builtin_amdgcn_mfma_f32_16x16x32_f16(
                    a[ri], bf[ni], acc[ri][ni], 0, 0, 0);
    };

    // prologue: order A0, W0, A1, W1, W2 -> waiting through W0 leaves 12
    loadA(aE, 0);
    issueW(&lds[0][0]);
    loadA(aO, 1);
    issueW(&lds[1][0]);
    issueW(&lds[2][0]);
    __builtin_amdgcn_sched_barrier(0);

    int wslot = 0;
    for (int t = 0; t < ns; t += 2) {
        // ---- phase A: stage t, regs aE, LDS slot wslot ----
        if (t < ns - 2)       asm volatile("s_waitcnt vmcnt(12)" ::: "memory");
        else if (t == ns - 2) asm volatile("s_waitcnt vmcnt(8)"  ::: "memory");
        else                  asm volatile("s_waitcnt vmcnt(0)"  ::: "memory");
        __builtin_amdgcn_sched_barrier(0);
        __builtin_amdgcn_s_barrier();
        __builtin_amdgcn_sched_barrier(0);
        {
            char* wp = &lds[wslot][0];
            step(wp, aE);
            __builtin_amdgcn_sched_barrier(0);
            asm volatile("s_waitcnt lgkmcnt(0)" ::: "memory");
            __builtin_amdgcn_sched_barrier(0);
            __builtin_amdgcn_s_barrier();
            __builtin_amdgcn_sched_barrier(0);
            if (t + 2 < ns) loadA(aE, t + 2);      // A two ahead (issue first)
            if (t + 3 < ns) issueW(wp);            // W three ahead -> same slot
            __builtin_amdgcn_sched_barrier(0);
        }
        wslot = (wslot == 2) ? 0 : wslot + 1;

        // ---- phase B: stage t+1, regs aO ----
        if (t + 1 < ns - 2)       asm volatile("s_waitcnt vmcnt(12)" ::: "memory");
        else if (t + 1 == ns - 2) asm volatile("s_waitcnt vmcnt(8)"  ::: "memory");
        else                      asm volatile("s_waitcnt vmcnt(0)"  ::: "memory");
        __builtin_amdgcn_sched_barrier(0);
        __builtin_amdgcn_s_barrier();
        __builtin_amdgcn_sched_barrier(0);
        {
            char* wp = &lds[wslot][0];
            step(wp, aO);
            __builtin_amdgcn_sched_barrier(0);
            asm volatile("s_waitcnt lgkmcnt(0)" ::: "memory");
            __builtin_amdgcn_sched_barrier(0);
            __builtin_amdgcn_s_barrier();
            __builtin_amdgcn_sched_barrier(0);
            if (t + 3 < ns) loadA(aO, t + 3);
            if (t + 4 < ns) issueW(wp);
            __builtin_amdgcn_sched_barrier(0);
        }
        wslot = (wslot == 2) ? 0 : wslot + 1;
    }

    // epilogue: D layout col=lane&15, row=(lane>>4)*4+reg  [m89-verified]
    f16* Pb = P + (size_t)y * (256 * DH);
#pragma unroll
    for (int ri = 0; ri < 4; ++ri) {
        int row = m0 + wm * 64 + ri * 16 + (q << 2);
#pragma unroll
        for (int ni = 0; ni < 4; ++ni) {
            int col = n0 + wn * 64 + ni * 16 + lc;
#pragma unroll
            for (int rg = 0; rg < 4; ++rg)
                Pb[(size_t)(row + rg) * DH + col] = (_Float16)acc[ri][ni][rg];
        }
    }
}

// ---------------- splitK reduce (f16 partials) + bias + relu ----------------
__global__ __launch_bounds__(256) void reduce_kernel(
    const f16* __restrict__ P, int S,
    const float* __restrict__ bias,
    f16* __restrict__ oh, float* __restrict__ out32) {
    const size_t n = 256 * DH;
    const size_t i = ((size_t)blockIdx.x * 256 + threadIdx.x) * 8;
    if (i >= n) return;
    float r[8];
    {
        float4 b0 = *(const float4*)(bias + (i % DH));
        float4 b1 = *(const float4*)(bias + (i % DH) + 4);
        r[0] = b0.x; r[1] = b0.y; r[2] = b0.z; r[3] = b0.w;
        r[4] = b1.x; r[5] = b1.y; r[6] = b1.z; r[7] = b1.w;
    }
    for (int j = 0; j < S; ++j) {
        f16x8 v = *(const f16x8*)(P + (size_t)j * n + i);
#pragma unroll
        for (int e = 0; e < 8; ++e) r[e] += (float)v[e];
    }
#pragma unroll
    for (int e = 0; e < 8; ++e) r[e] = fmaxf(r[e], 0.f);
    if (oh) {
        f16x8 h;
#pragma unroll
        for (int e = 0; e < 8; ++e) h[e] = (_Float16)r[e];
        *(f16x8*)(oh + i) = h;
    }
    if (out32) {
        float4 o0 = {r[0], r[1], r[2], r[3]};
        float4 o1 = {r[4], r[5], r[6], r[7]};
        *(float4*)(out32 + i) = o0;
        *(float4*)(out32 + i + 4) = o1;
    }
}

// ---------------- action head: softmax(X3[:, :8960] @ Wa + ba) --------------
__global__ __launch_bounds__(256) void action_kernel(
    const float* __restrict__ X3, const float* __restrict__ Wa,
    const float* __restrict__ ba, float* __restrict__ xact) {
    __shared__ float xs[SPLIT];
    __shared__ float red[256];
    const int row = blockIdx.x, t = threadIdx.x;
    const float* xr = X3 + (size_t)row * DH;
    for (int k = t * 4; k < SPLIT; k += 1024)
        *(float4*)&xs[k] = *(const float4*)(xr + k);
    __syncthreads();
    const int col = t & 63, kqq = t >> 6;
    float acc = 0.f;
    for (int k = kqq * 2240; k < (kqq + 1) * 2240; ++k)
        acc += xs[k] * Wa[(size_t)k * 64 + col];
    red[t] = acc;
    __syncthreads();
    if (t < 64) {
        float z = red[t] + red[t + 64] + red[t + 128] + red[t + 192] + ba[t];
        float mx = z;
        for (int off = 32; off; off >>= 1) mx = fmaxf(mx, __shfl_xor(mx, off));
        float e = expf(z - mx);
        float s = e;
        for (int off = 32; off; off >>= 1) s += __shfl_xor(s, off);
        xact[row * 64 + t] = e / s;
    }
}

// ---------------- selection head + final outputs ---------------------------
__global__ __launch_bounds__(256) void select_kernel(
    const float* __restrict__ X3, const float* __restrict__ Ws,
    const float* __restrict__ bs, const void* __restrict__ maskp,
    const float* __restrict__ u, const float* __restrict__ xact,
    float* __restrict__ out) {
    __shared__ float xs[256];
    __shared__ float psh[256];
    __shared__ float rr[4];
    __shared__ float bestv[4];
    __shared__ int besti[4];
    __shared__ int sIdx;
    __shared__ int smode;
    const int row = blockIdx.x, t = threadIdx.x;
    const int lane = t & 63, wid = t >> 6;

    // mask dtype detection: int32 {0,1} / bytes {0,1} / float {0.f,1.f}
    if (t < 64) {
        unsigned v = ((const unsigned*)maskp)[t];
        int okInt  = __all(v <= 1u);
        int okByte = __all((v & 0xFEFEFEFEu) == 0u);
        if (t == 0) smode = okInt ? 0 : (okByte ? 1 : 2);
    }
    xs[t] = X3[(size_t)row * DH + SPLIT + t];
    __syncthreads();

    bool mk;
    if (smode == 0)       mk = ((const int*)maskp)[row * 256 + t] != 0;
    else if (smode == 1)  mk = ((const unsigned char*)maskp)[row * 256 + t] != 0;
    else                  mk = ((const float*)maskp)[row * 256 + t] != 0.0f;

    float z = bs[t];
    for (int k = 0; k < 256; ++k)
        z += xs[k] * Ws[k * 256 + t];

    // softmax #1
    float v = z;
    for (int off = 32; off; off >>= 1) v = fmaxf(v, __shfl_xor(v, off));
    if (lane == 0) rr[wid] = v;
    __syncthreads();
    float m1 = fmaxf(fmaxf(rr[0], rr[1]), fmaxf(rr[2], rr[3]));
    __syncthreads();
    float e1 = expf(z - m1);
    v = e1;
    for (int off = 32; off; off >>= 1) v += __shfl_xor(v, off);
    if (lane == 0) rr[wid] = v;
    __syncthreads();
    float s1 = rr[0] + rr[1] + rr[2] + rr[3];
    __syncthreads();
    float p1 = e1 / s1;

    // mask, softmax #2
    float q = mk ? -1e9f : p1;
    v = q;
    for (int off = 32; off; off >>= 1) v = fmaxf(v, __shfl_xor(v, off));
    if (lane == 0) rr[wid] = v;
    __syncthreads();
    float m2 = fmaxf(fmaxf(rr[0], rr[1]), fmaxf(rr[2], rr[3]));
    __syncthreads();
    float e2 = expf(q - m2);
    v = e2;
    for (int off = 32; off; off >>= 1) v += __shfl_xor(v, off);
    if (lane == 0) rr[wid] = v;
    __syncthreads();
    float s2 = rr[0] + rr[1] + rr[2] + rr[3];
    float p2 = e2 / s2;
    psh[t] = p2;

    // gumbel scores + first-occurrence argmax
    float g = -logf(-logf(u[row * 256 + t]));
    float sc = mk ? -INFINITY : (logf(p2) + g);
    float bv = sc;
    int bi = t;
    for (int off = 32; off; off >>= 1) {
        float ov = __shfl_xor(bv, off);
        int oi = __shfl_xor(bi, off);
        if (ov > bv || (ov == bv && oi < bi)) { bv = ov; bi = oi; }
    }
    if (lane == 0) { bestv[wid] = bv; besti[wid] = bi; }
    __syncthreads();
    if (t == 0) {
        float fv = bestv[0];
        int fi = besti[0];
        for (int w = 1; w < 4; ++w)
            if (bestv[w] > fv || (bestv[w] == fv && besti[w] < fi)) {
                fv = bestv[w]; fi = besti[w];
            }
        sIdx = fi;
    }
    __syncthreads();
    const int idx = sIdx;
    const float sp = psh[idx];
    if (t < 64) out[row * 64 + t] = xact[row * 64 + t] * sp;
    if (t == 0) {
        out[256 * 64 + row * 2 + 0] = (float)(idx >> 4);
        out[256 * 64 + row * 2 + 1] = (float)(idx & 15);
    }
}

// ---------------------------------------------------------------------------
extern "C" void kernel_launch(void* const* d_in, const int* in_sizes, int n_in,
                              void* d_out, int out_size, void* d_ws, size_t ws_size,
                              hipStream_t stream) {
    const float* s  = (const float*)d_in[0];
    const void*  mask = d_in[1];
    const float* u  = (const float*)d_in[2];
    const float* W1 = (const float*)d_in[3];
    const float* b1 = (const float*)d_in[4];
    const float* W2 = (const float*)d_in[5];
    const float* b2 = (const float*)d_in[6];
    const float* W3 = (const float*)d_in[7];
    const float* b3 = (const float*)d_in[8];
    const float* Wa = (const float*)d_in[9];
    const float* ba = (const float*)d_in[10];
    const float* Ws = (const float*)d_in[11];
    const float* bs = (const float*)d_in[12];
    float* out = (float*)d_out;
    char* ws = (char*)d_ws;

    // workspace map:
    //   [0,        8,388,608)  A0 f16 [256][16384]   (reused by X2 after gemm1)
    //   [8388608, 13,107,200)  X1 f16 [256][9216]
    //   [13107200,22,544,384)  X3 f32 [256][9216]
    //   [22544384,22,609,920)  XA f32 [256][64]
    //   [22609920, ...)        P  f16 [S][256][9216]  (4.72 MB/plane)
    f16*   A0 = (f16*)(ws + 0);
    f16*   X1 = (f16*)(ws + 8388608);
    f16*   X2 = (f16*)(ws + 0);            // reuses dead A0
    float* X3 = (float*)(ws + 13107200);
    float* XA = (float*)(ws + 22544384);
    f16*   P  = (f16*)(ws + 22609920);

    const size_t pbytes = 4718592ull;      // one f16 splitK plane
    int yshift = (ws_size >= 22609920ull + 8 * pbytes) ? 3 : 2;
    const int S = 1 << yshift;

    cvt_kernel<<<2048, 256, 0, stream>>>(s, A0, 256 * 16384);

    const int nblk = (2 * 72) << yshift;   // 1152 @ S=8; y = bid & (S-1)
    gemm_kernel<<<nblk, 256, 0, stream>>>(A0, 16384, 16384 / S, yshift, W1, P);
    reduce_kernel<<<1152, 256, 0, stream>>>(P, S, b1, X1, nullptr);
    gemm_kernel<<<nblk, 256, 0, stream>>>(X1, DH, DH / S, yshift, W2, P);
    reduce_kernel<<<1152, 256, 0, stream>>>(P, S, b2, X2, nullptr);
    gemm_kernel<<<nblk, 256, 0, stream>>>(X2, DH, DH / S, yshift, W3, P);
    reduce_kernel<<<1152, 256, 0, stream>>>(P, S, b3, nullptr, X3);

    action_kernel<<<256, 256, 0, stream>>>(X3, Wa, ba, XA);
    select_kernel<<<256, 256, 0, stream>>>(X3, Ws, bs, mask, u, XA, out);
}

// Round 18
// 561.468 us; speedup vs baseline: 1.1471x; 1.1471x over previous
//
#include <hip/hip_runtime.h>
#include <hip/hip_fp16.h>

// ---------------------------------------------------------------------------
// MLPForwardPolicy — r16 champion with ONE change: all-DMA ring depth 2 -> 3.
//
// r17 lesson: A in VGPRs lets the compiler insert its own vmcnt waits for the
// register deps, draining the counted pipeline (r8/r9 mechanism). So keep ALL
// VMEM in global_load_lds and deepen the ring instead: lds[3][24576] (72 KB,
// 2 blocks/CU). 6 DMA instr/stage; prologue 0,1,2; steady vmcnt(12) = two
// stages in flight -> ~2.5-step (~1250cy) lead > ~900cy HBM latency ->
// stall-free. Tail: vmcnt(6) @ ns-2, vmcnt(0) @ ns-1. Slot(t+3) = slot(t)
// reused after the post-compute barrier. Decisive test: [8 waves/CU,
// stall-free] vs r16's [12 waves/CU, 1-step lead].
// Ranking: r16=561 r11=592 r7=606 r17=644 r10/r15=656 r3=663 r6=669.
// ---------------------------------------------------------------------------

typedef _Float16 f16;
typedef _Float16 f16x4 __attribute__((ext_vector_type(4)));
typedef _Float16 f16x8 __attribute__((ext_vector_type(8)));
typedef float f32x4 __attribute__((ext_vector_type(4)));

#define DH 9216
#define SPLIT 8960

__device__ __forceinline__ void gload16(const void* g, void* l) {
    __builtin_amdgcn_global_load_lds(
        (const __attribute__((address_space(1))) void*)g,
        (__attribute__((address_space(3))) void*)l, 16, 0, 0);
}

// ---------------- f32 -> f16 ----------------
__global__ void cvt_kernel(const float* __restrict__ in, f16* __restrict__ out, int n) {
    for (int i = (blockIdx.x * blockDim.x + threadIdx.x) * 4; i < n;
         i += gridDim.x * blockDim.x * 4) {
        float4 v = *(const float4*)(in + i);
        f16x4 h = {(_Float16)v.x, (_Float16)v.y, (_Float16)v.z, (_Float16)v.w};
        *(f16x4*)(out + i) = h;
    }
}

// ---------------- streaming GEMM: P[y] = A[128-row][Kh] @ W[Kh, 128-col] ----
// linear grid (2*72)<<yshift blocks of 256 threads; y = bid & (S-1)
// rem = bid >> yshift: m0 = (rem&1)*128, n0 = (rem>>1)*128
// 4 waves 2x2: wave(wm,wn) owns rows m0+wm*64..+64 x cols n0+wn*64..+64
__global__ __launch_bounds__(256, 2) void gemm_kernel(
    const f16* __restrict__ A, int K, int Kh, int yshift,
    const float* __restrict__ W,
    f16* __restrict__ P)   // [S][256][9216] f16 partials
{
    __shared__ __align__(16) char lds[3][24576];   // ring depth 3 (72 KB)
    const int bid  = blockIdx.x;
    const int y    = bid & ((1 << yshift) - 1);
    const int rem  = bid >> yshift;
    const int m0   = (rem & 1) << 7;
    const int n0   = (rem >> 1) << 7;
    const int tid  = threadIdx.x;
    const int lane = tid & 63;
    const int wid  = tid >> 6;
    const int wm   = wid >> 1, wn = wid & 1;
    const int kbase = y * Kh;
    const int ns   = Kh >> 5;                     // BK = 32

    f32x4 acc[4][4] = {};

    // ---- hoisted DMA source pointers (advance by one stage per issue) ----
    // W: granule g = tid + r*256 (1024 total): k = g>>5, p = g&31,
    //    src col-group cg = p ^ ((5*(k>>3)) & 31)
    const float* wsrc0;
    const float* wsrc1;
    const float* wsrc2;
    const float* wsrc3;
    {
        int g0 = tid,      k0 = g0 >> 5, c0 = (g0 & 31) ^ ((5 * (k0 >> 3)) & 31);
        int g1 = tid + 256, k1 = g1 >> 5, c1 = (g1 & 31) ^ ((5 * (k1 >> 3)) & 31);
        int g2 = tid + 512, k2 = g2 >> 5, c2 = (g2 & 31) ^ ((5 * (k2 >> 3)) & 31);
        int g3 = tid + 768, k3 = g3 >> 5, c3 = (g3 & 31) ^ ((5 * (k3 >> 3)) & 31);
        wsrc0 = W + (size_t)(kbase + k0) * DH + n0 + (c0 << 2);
        wsrc1 = W + (size_t)(kbase + k1) * DH + n0 + (c1 << 2);
        wsrc2 = W + (size_t)(kbase + k2) * DH + n0 + (c2 << 2);
        wsrc3 = W + (size_t)(kbase + k3) * DH + n0 + (c3 << 2);
    }
    // A: granule h = tid + r*256 (512 total): wmA = h>>8, ri = (h>>6)&3,
    //    q = (h>>4)&3, lc = h&15 -> A[m0 + wmA*64 + ri*16 + lc][kt + q*8..+8]
    const f16* asrc0;
    const f16* asrc1;
    {
        int h0 = tid, h1 = tid + 256;
        int r0 = m0 + ((h0 >> 8) << 6) + (((h0 >> 6) & 3) << 4) + (h0 & 15);
        int r1 = m0 + ((h1 >> 8) << 6) + (((h1 >> 6) & 3) << 4) + (h1 & 15);
        asrc0 = A + (size_t)r0 * K + kbase + (((h0 >> 4) & 3) << 3);
        asrc1 = A + (size_t)r1 * K + kbase + (((h1 >> 4) & 3) << 3);
    }

    auto issue = [&](int slot) {      // 6 DMA instr/thread; advance ptrs 1 stage
        char* dst = &lds[slot][0];
        gload16(wsrc0, dst + (size_t)tid * 16);          wsrc0 += 32 * DH;
        gload16(wsrc1, dst + (size_t)(tid + 256) * 16);  wsrc1 += 32 * DH;
        gload16(wsrc2, dst + (size_t)(tid + 512) * 16);  wsrc2 += 32 * DH;
        gload16(wsrc3, dst + (size_t)(tid + 768) * 16);  wsrc3 += 32 * DH;
        gload16(asrc0, dst + 16384 + (size_t)tid * 16);         asrc0 += 32;
        gload16(asrc1, dst + 16384 + (size_t)(tid + 256) * 16); asrc1 += 32;
    };

    const int q  = lane >> 4;
    const int lc = lane & 15;
    auto step = [&](int slot) {
        const float* wl = (const float*)&lds[slot][0];
        const f16*   al = (const f16*)&lds[slot][16384];
        f16x8 af[4], bf[4];
#pragma unroll
        for (int ri = 0; ri < 4; ++ri)      // lane-linear b128: conflict-free
            af[ri] = *(const f16x8*)(al + (((wm << 8) + (ri << 6) + lane) << 3));
        const int wbase = (q << 10) + (lc & 3);           // k = q*8 -> q*8*128
#pragma unroll
        for (int ni = 0; ni < 4; ++ni) {
            int p = ((wn << 4) + (ni << 2) + (lc >> 2)) ^ (5 * q);
            int fi = wbase + ((p & 31) << 2);
            f16x8 b;
#pragma unroll
            for (int j = 0; j < 8; ++j)
                b[j] = (_Float16)wl[fi + (j << 7)];
            bf[ni] = b;
        }
#pragma unroll
        for (int ri = 0; ri < 4; ++ri)
#pragma unroll
            for (int ni = 0; ni < 4; ++ni)
                acc[ri][ni] = __builtin_amdgcn_mfma_f32_16x16x32_f16(
                    af[ri], bf[ni], acc[ri][ni], 0, 0, 0);
    };

    // prologue: 3 stages in flight (18 DMA instr/thread)
    issue(0);
    issue(1);
    issue(2);
    __builtin_amdgcn_sched_barrier(0);

    int slot = 0;
    for (int t = 0; t < ns; ++t) {
        if (t < ns - 2)       asm volatile("s_waitcnt vmcnt(12)" ::: "memory");
        else if (t == ns - 2) asm volatile("s_waitcnt vmcnt(6)"  ::: "memory");
        else                  asm volatile("s_waitcnt vmcnt(0)"  ::: "memory");
        __builtin_amdgcn_sched_barrier(0);
        __builtin_amdgcn_s_barrier();
        __builtin_amdgcn_sched_barrier(0);
        step(slot);
        __builtin_amdgcn_sched_barrier(0);
        asm volatile("s_waitcnt lgkmcnt(0)" ::: "memory");
        __builtin_amdgcn_sched_barrier(0);
        __builtin_amdgcn_s_barrier();
        __builtin_amdgcn_sched_barrier(0);
        if (t + 3 < ns) {
            issue(slot);                 // stage t+3 into slot(t) (just drained)
            __builtin_amdgcn_sched_barrier(0);
        }
        slot = (slot == 2) ? 0 : slot + 1;
    }

    // epilogue: D layout col=lane&15, row=(lane>>4)*4+reg  [m89-verified]
    f16* Pb = P + (size_t)y * (256 * DH);
#pragma unroll
    for (int ri = 0; ri < 4; ++ri) {
        int row = m0 + wm * 64 + ri * 16 + (q << 2);
#pragma unroll
        for (int ni = 0; ni < 4; ++ni) {
            int col = n0 + wn * 64 + ni * 16 + lc;
#pragma unroll
            for (int rg = 0; rg < 4; ++rg)
                Pb[(size_t)(row + rg) * DH + col] = (_Float16)acc[ri][ni][rg];
        }
    }
}

// ---------------- splitK reduce (f16 partials) + bias + relu ----------------
__global__ __launch_bounds__(256) void reduce_kernel(
    const f16* __restrict__ P, int S,
    const float* __restrict__ bias,
    f16* __restrict__ oh, float* __restrict__ out32) {
    const size_t n = 256 * DH;
    const size_t i = ((size_t)blockIdx.x * 256 + threadIdx.x) * 8;
    if (i >= n) return;
    float r[8];
    {
        float4 b0 = *(const float4*)(bias + (i % DH));
        float4 b1 = *(const float4*)(bias + (i % DH) + 4);
        r[0] = b0.x; r[1] = b0.y; r[2] = b0.z; r[3] = b0.w;
        r[4] = b1.x; r[5] = b1.y; r[6] = b1.z; r[7] = b1.w;
    }
    for (int j = 0; j < S; ++j) {
        f16x8 v = *(const f16x8*)(P + (size_t)j * n + i);
#pragma unroll
        for (int e = 0; e < 8; ++e) r[e] += (float)v[e];
    }
#pragma unroll
    for (int e = 0; e < 8; ++e) r[e] = fmaxf(r[e], 0.f);
    if (oh) {
        f16x8 h;
#pragma unroll
        for (int e = 0; e < 8; ++e) h[e] = (_Float16)r[e];
        *(f16x8*)(oh + i) = h;
    }
    if (out32) {
        float4 o0 = {r[0], r[1], r[2], r[3]};
        float4 o1 = {r[4], r[5], r[6], r[7]};
        *(float4*)(out32 + i) = o0;
        *(float4*)(out32 + i + 4) = o1;
    }
}

// ---------------- action head: softmax(X3[:, :8960] @ Wa + ba) --------------
__global__ __launch_bounds__(256) void action_kernel(
    const float* __restrict__ X3, const float* __restrict__ Wa,
    const float* __restrict__ ba, float* __restrict__ xact) {
    __shared__ float xs[SPLIT];
    __shared__ float red[256];
    const int row = blockIdx.x, t = threadIdx.x;
    const float* xr = X3 + (size_t)row * DH;
    for (int k = t * 4; k < SPLIT; k += 1024)
        *(float4*)&xs[k] = *(const float4*)(xr + k);
    __syncthreads();
    const int col = t & 63, kqq = t >> 6;
    float acc = 0.f;
    for (int k = kqq * 2240; k < (kqq + 1) * 2240; ++k)
        acc += xs[k] * Wa[(size_t)k * 64 + col];
    red[t] = acc;
    __syncthreads();
    if (t < 64) {
        float z = red[t] + red[t + 64] + red[t + 128] + red[t + 192] + ba[t];
        float mx = z;
        for (int off = 32; off; off >>= 1) mx = fmaxf(mx, __shfl_xor(mx, off));
        float e = expf(z - mx);
        float s = e;
        for (int off = 32; off; off >>= 1) s += __shfl_xor(s, off);
        xact[row * 64 + t] = e / s;
    }
}

// ---------------- selection head + final outputs ---------------------------
__global__ __launch_bounds__(256) void select_kernel(
    const float* __restrict__ X3, const float* __restrict__ Ws,
    const float* __restrict__ bs, const void* __restrict__ maskp,
    const float* __restrict__ u, const float* __restrict__ xact,
    float* __restrict__ out) {
    __shared__ float xs[256];
    __shared__ float psh[256];
    __shared__ float rr[4];
    __shared__ float bestv[4];
    __shared__ int besti[4];
    __shared__ int sIdx;
    __shared__ int smode;
    const int row = blockIdx.x, t = threadIdx.x;
    const int lane = t & 63, wid = t >> 6;

    // mask dtype detection: int32 {0,1} / bytes {0,1} / float {0.f,1.f}
    if (t < 64) {
        unsigned v = ((const unsigned*)maskp)[t];
        int okInt  = __all(v <= 1u);
        int okByte = __all((v & 0xFEFEFEFEu) == 0u);
        if (t == 0) smode = okInt ? 0 : (okByte ? 1 : 2);
    }
    xs[t] = X3[(size_t)row * DH + SPLIT + t];
    __syncthreads();

    bool mk;
    if (smode == 0)       mk = ((const int*)maskp)[row * 256 + t] != 0;
    else if (smode == 1)  mk = ((const unsigned char*)maskp)[row * 256 + t] != 0;
    else                  mk = ((const float*)maskp)[row * 256 + t] != 0.0f;

    float z = bs[t];
    for (int k = 0; k < 256; ++k)
        z += xs[k] * Ws[k * 256 + t];

    // softmax #1
    float v = z;
    for (int off = 32; off; off >>= 1) v = fmaxf(v, __shfl_xor(v, off));
    if (lane == 0) rr[wid] = v;
    __syncthreads();
    float m1 = fmaxf(fmaxf(rr[0], rr[1]), fmaxf(rr[2], rr[3]));
    __syncthreads();
    float e1 = expf(z - m1);
    v = e1;
    for (int off = 32; off; off >>= 1) v += __shfl_xor(v, off);
    if (lane == 0) rr[wid] = v;
    __syncthreads();
    float s1 = rr[0] + rr[1] + rr[2] + rr[3];
    __syncthreads();
    float p1 = e1 / s1;

    // mask, softmax #2
    float q = mk ? -1e9f : p1;
    v = q;
    for (int off = 32; off; off >>= 1) v = fmaxf(v, __shfl_xor(v, off));
    if (lane == 0) rr[wid] = v;
    __syncthreads();
    float m2 = fmaxf(fmaxf(rr[0], rr[1]), fmaxf(rr[2], rr[3]));
    __syncthreads();
    float e2 = expf(q - m2);
    v = e2;
    for (int off = 32; off; off >>= 1) v += __shfl_xor(v, off);
    if (lane == 0) rr[wid] = v;
    __syncthreads();
    float s2 = rr[0] + rr[1] + rr[2] + rr[3];
    float p2 = e2 / s2;
    psh[t] = p2;

    // gumbel scores + first-occurrence argmax
    float g = -logf(-logf(u[row * 256 + t]));
    float sc = mk ? -INFINITY : (logf(p2) + g);
    float bv = sc;
    int bi = t;
    for (int off = 32; off; off >>= 1) {
        float ov = __shfl_xor(bv, off);
        int oi = __shfl_xor(bi, off);
        if (ov > bv || (ov == bv && oi < bi)) { bv = ov; bi = oi; }
    }
    if (lane == 0) { bestv[wid] = bv; besti[wid] = bi; }
    __syncthreads();
    if (t == 0) {
        float fv = bestv[0];
        int fi = besti[0];
        for (int w = 1; w < 4; ++w)
            if (bestv[w] > fv || (bestv[w] == fv && besti[w] < fi)) {
                fv = bestv[w]; fi = besti[w];
            }
        sIdx = fi;
    }
    __syncthreads();
    const int idx = sIdx;
    const float sp = psh[idx];
    if (t < 64) out[row * 64 + t] = xact[row * 64 + t] * sp;
    if (t == 0) {
        out[256 * 64 + row * 2 + 0] = (float)(idx >> 4);
        out[256 * 64 + row * 2 + 1] = (float)(idx & 15);
    }
}

// ---------------------------------------------------------------------------
extern "C" void kernel_launch(void* const* d_in, const int* in_sizes, int n_in,
                              void* d_out, int out_size, void* d_ws, size_t ws_size,
                              hipStream_t stream) {
    const float* s  = (const float*)d_in[0];
    const void*  mask = d_in[1];
    const float* u  = (const float*)d_in[2];
    const float* W1 = (const float*)d_in[3];
    const float* b1 = (const float*)d_in[4];
    const float* W2 = (const float*)d_in[5];
    const float* b2 = (const float*)d_in[6];
    const float* W3 = (const float*)d_in[7];
    const float* b3 = (const float*)d_in[8];
    const float* Wa = (const float*)d_in[9];
    const float* ba = (const float*)d_in[10];
    const float* Ws = (const float*)d_in[11];
    const float* bs = (const float*)d_in[12];
    float* out = (float*)d_out;
    char* ws = (char*)d_ws;

    // workspace map:
    //   [0,        8,388,608)  A0 f16 [256][16384]   (reused by X2 after gemm1)
    //   [8388608, 13,107,200)  X1 f16 [256][9216]
    //   [13107200,22,544,384)  X3 f32 [256][9216]
    //   [22544384,22,609,920)  XA f32 [256][64]
    //   [22609920, ...)        P  f16 [S][256][9216]  (4.72 MB/plane)
    f16*   A0 = (f16*)(ws + 0);
    f16*   X1 = (f16*)(ws + 8388608);
    f16*   X2 = (f16*)(ws + 0);            // reuses dead A0
    float* X3 = (float*)(ws + 13107200);
    float* XA = (float*)(ws + 22544384);
    f16*   P  = (f16*)(ws + 22609920);

    const size_t pbytes = 4718592ull;      // one f16 splitK plane
    int yshift = (ws_size >= 22609920ull + 8 * pbytes) ? 3 : 2;
    const int S = 1 << yshift;

    cvt_kernel<<<2048, 256, 0, stream>>>(s, A0, 256 * 16384);

    const int nblk = (2 * 72) << yshift;   // 1152 @ S=8; y = bid & (S-1)
    gemm_kernel<<<nblk, 256, 0, stream>>>(A0, 16384, 16384 / S, yshift, W1, P);
    reduce_kernel<<<1152, 256, 0, stream>>>(P, S, b1, X1, nullptr);
    gemm_kernel<<<nblk, 256, 0, stream>>>(X1, DH, DH / S, yshift, W2, P);
    reduce_kernel<<<1152, 256, 0, stream>>>(P, S, b2, X2, nullptr);
    gemm_kernel<<<nblk, 256, 0, stream>>>(X2, DH, DH / S, yshift, W3, P);
    reduce_kernel<<<1152, 256, 0, stream>>>(P, S, b3, nullptr, X3);

    action_kernel<<<256, 256, 0, stream>>>(X3, Wa, ba, XA);
    select_kernel<<<256, 256, 0, stream>>>(X3, Ws, bs, mask, u, XA, out);
}

// Round 19
// 514.359 us; speedup vs baseline: 1.2521x; 1.0916x over previous
//
#include <hip/hip_runtime.h>
#include <hip/hip_fp16.h>

// ---------------------------------------------------------------------------
// MLPForwardPolicy — r16 champion + PACKED A layout (coalesced A-DMA).
//
// r18 tie (depth-3@8w == depth-2@12w == 561) -> limiter is invariant to
// latency-lead/occupancy. The remaining pathological access: A-granule DMA is
// a 64-way 16B scatter (each lane a different row, stride 32KB), re-staged
// 72x per panel. Fix: store A0/X1/X2 in GEMM-staging granule order
//   Ap[(tk*2 + mhalf)*8192 + h*16],  h = [wmA:1][ri:2][q:2][lc:4]
// (tk = k>>5 global, S-agnostic). A-staging = contiguous 16B/lane runs;
// scatter paid once by producers (cvt/reduce, ~5 MB) not 72x by stager.
// GEMM core byte-identical to r16: depth-2 ring, vmcnt(6)/0, 2 barriers/step,
// f16 splitK partials, 3 blocks/CU.
// Ranking: r16/r18=561 r11=592 r7=606 r17=644 r10/r15=656 r3=663.
// ---------------------------------------------------------------------------

typedef _Float16 f16;
typedef _Float16 f16x4 __attribute__((ext_vector_type(4)));
typedef _Float16 f16x8 __attribute__((ext_vector_type(8)));
typedef float f32x4 __attribute__((ext_vector_type(4)));

#define DH 9216
#define SPLIT 8960

__device__ __forceinline__ void gload16(const void* g, void* l) {
    __builtin_amdgcn_global_load_lds(
        (const __attribute__((address_space(1))) void*)g,
        (__attribute__((address_space(3))) void*)l, 16, 0, 0);
}

// packed-granule byte offset for element (row, k):  j = k & 7 within f16x8
__device__ __forceinline__ size_t pk_off(int row, int k) {
    int tk = k >> 5, q = (k >> 3) & 3;
    int mhalf = row >> 7, wmA = (row >> 6) & 1, ri = (row >> 4) & 3, lc = row & 15;
    int h = (wmA << 8) | (ri << 6) | (q << 4) | lc;
    return (size_t)(tk * 2 + mhalf) * 8192 + (size_t)h * 16;
}

// ---------------- f32 -> packed f16 granules (for A0) ----------------
__global__ void cvt_kernel(const float* __restrict__ in, char* __restrict__ outp) {
    // one thread = 8 consecutive k at fixed row; 2048 blocks x 256 thr
    int idx = blockIdx.x * blockDim.x + threadIdx.x;   // [0, 524288)
    int row = idx >> 11;                               // 16384/8 = 2048 per row
    int k8  = (idx & 2047) << 3;
    const float* src = in + ((size_t)row << 14) + k8;
    f16x8 h;
#pragma unroll
    for (int j = 0; j < 8; ++j) h[j] = (_Float16)src[j];
    *(f16x8*)(outp + pk_off(row, k8)) = h;
}

// ---------------- streaming GEMM: P[y] = A[128-row][Kh] @ W[Kh, 128-col] ----
// linear grid (2*72)<<yshift blocks of 256 threads; y = bid & (S-1)
// rem = bid >> yshift: m0 = (rem&1)*128, n0 = (rem>>1)*128
// 4 waves 2x2: wave(wm,wn) owns rows m0+wm*64..+64 x cols n0+wn*64..+64
__global__ __launch_bounds__(256, 3) void gemm_kernel(
    const char* __restrict__ Ap, int K, int Kh, int yshift,
    const float* __restrict__ W,
    f16* __restrict__ P)   // [S][256][9216] f16 partials
{
    __shared__ __align__(16) char lds[2][24576];
    const int bid  = blockIdx.x;
    const int y    = bid & ((1 << yshift) - 1);
    const int rem  = bid >> yshift;
    const int m0   = (rem & 1) << 7;
    const int n0   = (rem >> 1) << 7;
    const int tid  = threadIdx.x;
    const int lane = tid & 63;
    const int wid  = tid >> 6;
    const int wm   = wid >> 1, wn = wid & 1;
    const int kbase = y * Kh;
    const int ns   = Kh >> 5;                     // BK = 32

    f32x4 acc[4][4] = {};

    // ---- hoisted W DMA source pointers (advance one stage per issue) ----
    // W: granule g = tid + r*256 (1024 total): k = g>>5, p = g&31,
    //    src col-group cg = p ^ ((5*(k>>3)) & 31)
    const float* wsrc0;
    const float* wsrc1;
    const float* wsrc2;
    const float* wsrc3;
    {
        int g0 = tid,      k0 = g0 >> 5, c0 = (g0 & 31) ^ ((5 * (k0 >> 3)) & 31);
        int g1 = tid + 256, k1 = g1 >> 5, c1 = (g1 & 31) ^ ((5 * (k1 >> 3)) & 31);
        int g2 = tid + 512, k2 = g2 >> 5, c2 = (g2 & 31) ^ ((5 * (k2 >> 3)) & 31);
        int g3 = tid + 768, k3 = g3 >> 5, c3 = (g3 & 31) ^ ((5 * (k3 >> 3)) & 31);
        wsrc0 = W + (size_t)(kbase + k0) * DH + n0 + (c0 << 2);
        wsrc1 = W + (size_t)(kbase + k1) * DH + n0 + (c1 << 2);
        wsrc2 = W + (size_t)(kbase + k2) * DH + n0 + (c2 << 2);
        wsrc3 = W + (size_t)(kbase + k3) * DH + n0 + (c3 << 2);
    }
    // packed A: stage t = 8 KB contiguous at ap + t*16384 (+mhalf*8192)
    const char* ap = Ap + (size_t)(y * (Kh >> 5) * 2 + (m0 >> 7)) * 8192;

    auto issue = [&](int slot) {      // 6 DMA instr/thread; advance ptrs 1 stage
        char* dst = &lds[slot][0];
        gload16(wsrc0, dst + (size_t)tid * 16);          wsrc0 += 32 * DH;
        gload16(wsrc1, dst + (size_t)(tid + 256) * 16);  wsrc1 += 32 * DH;
        gload16(wsrc2, dst + (size_t)(tid + 512) * 16);  wsrc2 += 32 * DH;
        gload16(wsrc3, dst + (size_t)(tid + 768) * 16);  wsrc3 += 32 * DH;
        gload16(ap + (size_t)tid * 16,        dst + 16384 + (size_t)tid * 16);
        gload16(ap + (size_t)tid * 16 + 4096, dst + 16384 + (size_t)tid * 16 + 4096);
        ap += 16384;
    };

    const int q  = lane >> 4;
    const int lc = lane & 15;
    auto step = [&](int slot) {
        const float* wl = (const float*)&lds[slot][0];
        const f16*   al = (const f16*)&lds[slot][16384];
        f16x8 af[4], bf[4];
#pragma unroll
        for (int ri = 0; ri < 4; ++ri)      // lane-linear b128: conflict-free
            af[ri] = *(const f16x8*)(al + (((wm << 8) + (ri << 6) + lane) << 3));
        const int wbase = (q << 10) + (lc & 3);           // k = q*8 -> q*8*128
#pragma unroll
        for (int ni = 0; ni < 4; ++ni) {
            int p = ((wn << 4) + (ni << 2) + (lc >> 2)) ^ (5 * q);
            int fi = wbase + ((p & 31) << 2);
            f16x8 b;
#pragma unroll
            for (int j = 0; j < 8; ++j)
                b[j] = (_Float16)wl[fi + (j << 7)];
            bf[ni] = b;
        }
#pragma unroll
        for (int ri = 0; ri < 4; ++ri)
#pragma unroll
            for (int ni = 0; ni < 4; ++ni)
                acc[ri][ni] = __builtin_amdgcn_mfma_f32_16x16x32_f16(
                    af[ri], bf[ni], acc[ri][ni], 0, 0, 0);
    };

    issue(0);
    issue(1);
    __builtin_amdgcn_sched_barrier(0);

    for (int t = 0; t < ns; ++t) {
        if (t + 1 < ns) asm volatile("s_waitcnt vmcnt(6)" ::: "memory");
        else            asm volatile("s_waitcnt vmcnt(0)" ::: "memory");
        __builtin_amdgcn_sched_barrier(0);
        __builtin_amdgcn_s_barrier();
        __builtin_amdgcn_sched_barrier(0);
        step(t & 1);
        __builtin_amdgcn_sched_barrier(0);
        asm volatile("s_waitcnt lgkmcnt(0)" ::: "memory");
        __builtin_amdgcn_sched_barrier(0);
        __builtin_amdgcn_s_barrier();
        __builtin_amdgcn_sched_barrier(0);
        if (t + 2 < ns) {
            issue(t & 1);
            __builtin_amdgcn_sched_barrier(0);
        }
    }

    // epilogue: D layout col=lane&15, row=(lane>>4)*4+reg  [m89-verified]
    f16* Pb = P + (size_t)y * (256 * DH);
#pragma unroll
    for (int ri = 0; ri < 4; ++ri) {
        int row = m0 + wm * 64 + ri * 16 + (q << 2);
#pragma unroll
        for (int ni = 0; ni < 4; ++ni) {
            int col = n0 + wn * 64 + ni * 16 + lc;
#pragma unroll
            for (int rg = 0; rg < 4; ++rg)
                Pb[(size_t)(row + rg) * DH + col] = (_Float16)acc[ri][ni][rg];
        }
    }
}

// ---------------- splitK reduce (f16 partials) + bias + relu ----------------
// oh != null: write PACKED granules (layout = pk_off, DH-keyed)
__global__ __launch_bounds__(256) void reduce_kernel(
    const f16* __restrict__ P, int S,
    const float* __restrict__ bias,
    char* __restrict__ ohp, float* __restrict__ out32) {
    const size_t n = 256 * DH;
    const size_t i = ((size_t)blockIdx.x * 256 + threadIdx.x) * 8;
    if (i >= n) return;
    const int row = (int)(i / DH);
    const int d   = (int)(i % DH);
    float r[8];
    {
        float4 b0 = *(const float4*)(bias + d);
        float4 b1 = *(const float4*)(bias + d + 4);
        r[0] = b0.x; r[1] = b0.y; r[2] = b0.z; r[3] = b0.w;
        r[4] = b1.x; r[5] = b1.y; r[6] = b1.z; r[7] = b1.w;
    }
    for (int j = 0; j < S; ++j) {
        f16x8 v = *(const f16x8*)(P + (size_t)j * n + i);
#pragma unroll
        for (int e = 0; e < 8; ++e) r[e] += (float)v[e];
    }
#pragma unroll
    for (int e = 0; e < 8; ++e) r[e] = fmaxf(r[e], 0.f);
    if (ohp) {
        f16x8 h;
#pragma unroll
        for (int e = 0; e < 8; ++e) h[e] = (_Float16)r[e];
        *(f16x8*)(ohp + pk_off(row, d)) = h;
    }
    if (out32) {
        float4 o0 = {r[0], r[1], r[2], r[3]};
        float4 o1 = {r[4], r[5], r[6], r[7]};
        *(float4*)(out32 + i) = o0;
        *(float4*)(out32 + i + 4) = o1;
    }
}

// ---------------- action head: softmax(X3[:, :8960] @ Wa + ba) --------------
__global__ __launch_bounds__(256) void action_kernel(
    const float* __restrict__ X3, const float* __restrict__ Wa,
    const float* __restrict__ ba, float* __restrict__ xact) {
    __shared__ float xs[SPLIT];
    __shared__ float red[256];
    const int row = blockIdx.x, t = threadIdx.x;
    const float* xr = X3 + (size_t)row * DH;
    for (int k = t * 4; k < SPLIT; k += 1024)
        *(float4*)&xs[k] = *(const float4*)(xr + k);
    __syncthreads();
    const int col = t & 63, kqq = t >> 6;
    float acc = 0.f;
    for (int k = kqq * 2240; k < (kqq + 1) * 2240; ++k)
        acc += xs[k] * Wa[(size_t)k * 64 + col];
    red[t] = acc;
    __syncthreads();
    if (t < 64) {
        float z = red[t] + red[t + 64] + red[t + 128] + red[t + 192] + ba[t];
        float mx = z;
        for (int off = 32; off; off >>= 1) mx = fmaxf(mx, __shfl_xor(mx, off));
        float e = expf(z - mx);
        float s = e;
        for (int off = 32; off; off >>= 1) s += __shfl_xor(s, off);
        xact[row * 64 + t] = e / s;
    }
}

// ---------------- selection head + final outputs ---------------------------
__global__ __launch_bounds__(256) void select_kernel(
    const float* __restrict__ X3, const float* __restrict__ Ws,
    const float* __restrict__ bs, const void* __restrict__ maskp,
    const float* __restrict__ u, const float* __restrict__ xact,
    float* __restrict__ out) {
    __shared__ float xs[256];
    __shared__ float psh[256];
    __shared__ float rr[4];
    __shared__ float bestv[4];
    __shared__ int besti[4];
    __shared__ int sIdx;
    __shared__ int smode;
    const int row = blockIdx.x, t = threadIdx.x;
    const int lane = t & 63, wid = t >> 6;

    // mask dtype detection: int32 {0,1} / bytes {0,1} / float {0.f,1.f}
    if (t < 64) {
        unsigned v = ((const unsigned*)maskp)[t];
        int okInt  = __all(v <= 1u);
        int okByte = __all((v & 0xFEFEFEFEu) == 0u);
        if (t == 0) smode = okInt ? 0 : (okByte ? 1 : 2);
    }
    xs[t] = X3[(size_t)row * DH + SPLIT + t];
    __syncthreads();

    bool mk;
    if (smode == 0)       mk = ((const int*)maskp)[row * 256 + t] != 0;
    else if (smode == 1)  mk = ((const unsigned char*)maskp)[row * 256 + t] != 0;
    else                  mk = ((const float*)maskp)[row * 256 + t] != 0.0f;

    float z = bs[t];
    for (int k = 0; k < 256; ++k)
        z += xs[k] * Ws[k * 256 + t];

    // softmax #1
    float v = z;
    for (int off = 32; off; off >>= 1) v = fmaxf(v, __shfl_xor(v, off));
    if (lane == 0) rr[wid] = v;
    __syncthreads();
    float m1 = fmaxf(fmaxf(rr[0], rr[1]), fmaxf(rr[2], rr[3]));
    __syncthreads();
    float e1 = expf(z - m1);
    v = e1;
    for (int off = 32; off; off >>= 1) v += __shfl_xor(v, off);
    if (lane == 0) rr[wid] = v;
    __syncthreads();
    float s1 = rr[0] + rr[1] + rr[2] + rr[3];
    __syncthreads();
    float p1 = e1 / s1;

    // mask, softmax #2
    float q = mk ? -1e9f : p1;
    v = q;
    for (int off = 32; off; off >>= 1) v = fmaxf(v, __shfl_xor(v, off));
    if (lane == 0) rr[wid] = v;
    __syncthreads();
    float m2 = fmaxf(fmaxf(rr[0], rr[1]), fmaxf(rr[2], rr[3]));
    __syncthreads();
    float e2 = expf(q - m2);
    v = e2;
    for (int off = 32; off; off >>= 1) v += __shfl_xor(v, off);
    if (lane == 0) rr[wid] = v;
    __syncthreads();
    float s2 = rr[0] + rr[1] + rr[2] + rr[3];
    float p2 = e2 / s2;
    psh[t] = p2;

    // gumbel scores + first-occurrence argmax
    float g = -logf(-logf(u[row * 256 + t]));
    float sc = mk ? -INFINITY : (logf(p2) + g);
    float bv = sc;
    int bi = t;
    for (int off = 32; off; off >>= 1) {
        float ov = __shfl_xor(bv, off);
        int oi = __shfl_xor(bi, off);
        if (ov > bv || (ov == bv && oi < bi)) { bv = ov; bi = oi; }
    }
    if (lane == 0) { bestv[wid] = bv; besti[wid] = bi; }
    __syncthreads();
    if (t == 0) {
        float fv = bestv[0];
        int fi = besti[0];
        for (int w = 1; w < 4; ++w)
            if (bestv[w] > fv || (bestv[w] == fv && besti[w] < fi)) {
                fv = bestv[w]; fi = besti[w];
            }
        sIdx = fi;
    }
    __syncthreads();
    const int idx = sIdx;
    const float sp = psh[idx];
    if (t < 64) out[row * 64 + t] = xact[row * 64 + t] * sp;
    if (t == 0) {
        out[256 * 64 + row * 2 + 0] = (float)(idx >> 4);
        out[256 * 64 + row * 2 + 1] = (float)(idx & 15);
    }
}

// ---------------------------------------------------------------------------
extern "C" void kernel_launch(void* const* d_in, const int* in_sizes, int n_in,
                              void* d_out, int out_size, void* d_ws, size_t ws_size,
                              hipStream_t stream) {
    const float* s  = (const float*)d_in[0];
    const void*  mask = d_in[1];
    const float* u  = (const float*)d_in[2];
    const float* W1 = (const float*)d_in[3];
    const float* b1 = (const float*)d_in[4];
    const float* W2 = (const float*)d_in[5];
    const float* b2 = (const float*)d_in[6];
    const float* W3 = (const float*)d_in[7];
    const float* b3 = (const float*)d_in[8];
    const float* Wa = (const float*)d_in[9];
    const float* ba = (const float*)d_in[10];
    const float* Ws = (const float*)d_in[11];
    const float* bs = (const float*)d_in[12];
    float* out = (float*)d_out;
    char* ws = (char*)d_ws;

    // workspace map (packed A layouts same sizes as before):
    //   [0,        8,388,608)  A0p packed f16 (K=16384)   (reused by X2p)
    //   [8388608, 13,107,200)  X1p packed f16 (K=9216)
    //   [13107200,22,544,384)  X3 f32 [256][9216]
    //   [22544384,22,609,920)  XA f32 [256][64]
    //   [22609920, ...)        P  f16 [S][256][9216]  (4.72 MB/plane)
    char*  A0p = ws + 0;
    char*  X1p = ws + 8388608;
    char*  X2p = ws + 0;                   // reuses dead A0p
    float* X3  = (float*)(ws + 13107200);
    float* XA  = (float*)(ws + 22544384);
    f16*   P   = (f16*)(ws + 22609920);

    const size_t pbytes = 4718592ull;      // one f16 splitK plane
    int yshift = (ws_size >= 22609920ull + 8 * pbytes) ? 3 : 2;
    const int S = 1 << yshift;

    cvt_kernel<<<2048, 256, 0, stream>>>(s, A0p);

    const int nblk = (2 * 72) << yshift;   // 1152 @ S=8; y = bid & (S-1)
    gemm_kernel<<<nblk, 256, 0, stream>>>(A0p, 16384, 16384 / S, yshift, W1, P);
    reduce_kernel<<<1152, 256, 0, stream>>>(P, S, b1, X1p, nullptr);
    gemm_kernel<<<nblk, 256, 0, stream>>>(X1p, DH, DH / S, yshift, W2, P);
    reduce_kernel<<<1152, 256, 0, stream>>>(P, S, b2, X2p, nullptr);
    gemm_kernel<<<nblk, 256, 0, stream>>>(X2p, DH, DH / S, yshift, W3, P);
    reduce_kernel<<<1152, 256, 0, stream>>>(P, S, b3, nullptr, X3);

    action_kernel<<<256, 256, 0, stream>>>(X3, Wa, ba, XA);
    select_kernel<<<256, 256, 0, stream>>>(X3, Ws, bs, mask, u, XA, out);
}

// Round 20
// 499.123 us; speedup vs baseline: 1.2904x; 1.0305x over previous
//
#include <hip/hip_runtime.h>
#include <hip/hip_fp16.h>

// ---------------------------------------------------------------------------
// MLPForwardPolicy — r19 + BM=256 (W streamed exactly once; DMA bytes -33%).
//
// Model (r16/r18/r19): GEMM time tracks total DMA-path bytes (~14 B/cy/CU),
// not unique HBM bytes. r19 G1 moved 1.77 GB (W 604 HBM + 604 L2-dup m-pair
// + A 590). This round: BM=256 per block -> W once: G1 = 1.19 GB, G2/3 =
// 0.67 GB. 4-wave blocks kept (r12's failure was 8-wave lockstep, not BM):
// wave = 128 rows x 64 cols, acc[8][4] (~200 VGPR, cap 256 @ (256,2)).
// Stage = W 16 KB + packed-A 16 KB (both m-halves contiguous) = 32 KB,
// ring-2 = 64 KB -> 2 blocks/CU (8 waves/CU; r18 proved parity with 12).
// vmcnt(8) steady / 0 tail; grid 72x8=576.
// Ranking: r19=514 r16/r18=561 r11=592 r7=606 r17=644 r10/r15=656.
// ---------------------------------------------------------------------------

typedef _Float16 f16;
typedef _Float16 f16x4 __attribute__((ext_vector_type(4)));
typedef _Float16 f16x8 __attribute__((ext_vector_type(8)));
typedef float f32x4 __attribute__((ext_vector_type(4)));

#define DH 9216
#define SPLIT 8960

__device__ __forceinline__ void gload16(const void* g, void* l) {
    __builtin_amdgcn_global_load_lds(
        (const __attribute__((address_space(1))) void*)g,
        (__attribute__((address_space(3))) void*)l, 16, 0, 0);
}

// packed-granule byte offset for element (row, k)
__device__ __forceinline__ size_t pk_off(int row, int k) {
    int tk = k >> 5, q = (k >> 3) & 3;
    int mhalf = row >> 7, wmA = (row >> 6) & 1, ri = (row >> 4) & 3, lc = row & 15;
    int h = (wmA << 8) | (ri << 6) | (q << 4) | lc;
    return (size_t)(tk * 2 + mhalf) * 8192 + (size_t)h * 16;
}

// ---------------- f32 -> packed f16 granules (for A0) ----------------
__global__ void cvt_kernel(const float* __restrict__ in, char* __restrict__ outp) {
    int idx = blockIdx.x * blockDim.x + threadIdx.x;   // [0, 524288)
    int row = idx >> 11;
    int k8  = (idx & 2047) << 3;
    const float* src = in + ((size_t)row << 14) + k8;
    f16x8 h;
#pragma unroll
    for (int j = 0; j < 8; ++j) h[j] = (_Float16)src[j];
    *(f16x8*)(outp + pk_off(row, k8)) = h;
}

// ---------------- streaming GEMM: P[y] = A[256,Kh] @ W[Kh, 128-col] ---------
// linear grid 72<<yshift blocks of 256 threads; y = bid & (S-1)
// n0 = (bid >> yshift) * 128
// 4 waves 2x2: wave(wm,wn) owns rows wm*128..+128 x cols n0+wn*64..+64
__global__ __launch_bounds__(256, 2) void gemm_kernel(
    const char* __restrict__ Ap, int K, int Kh, int yshift,
    const float* __restrict__ W,
    f16* __restrict__ P)   // [S][256][9216] f16 partials
{
    __shared__ __align__(16) char lds[2][32768];   // [W 16K][A 16K] x2
    const int bid  = blockIdx.x;
    const int y    = bid & ((1 << yshift) - 1);
    const int n0   = (bid >> yshift) << 7;
    const int tid  = threadIdx.x;
    const int lane = tid & 63;
    const int wid  = tid >> 6;
    const int wm   = wid >> 1, wn = wid & 1;
    const int kbase = y * Kh;
    const int ns   = Kh >> 5;                     // BK = 32 (64 or 36)

    f32x4 acc[8][4] = {};

    // ---- hoisted W DMA source pointers ----
    // granule g = tid + r*256 (1024): k = g>>5, p = g&31,
    // src col-group cg = p ^ ((5*(k>>3)) & 31)
    const float* wsrc0;
    const float* wsrc1;
    const float* wsrc2;
    const float* wsrc3;
    {
        int g0 = tid,      k0 = g0 >> 5, c0 = (g0 & 31) ^ ((5 * (k0 >> 3)) & 31);
        int g1 = tid + 256, k1 = g1 >> 5, c1 = (g1 & 31) ^ ((5 * (k1 >> 3)) & 31);
        int g2 = tid + 512, k2 = g2 >> 5, c2 = (g2 & 31) ^ ((5 * (k2 >> 3)) & 31);
        int g3 = tid + 768, k3 = g3 >> 5, c3 = (g3 & 31) ^ ((5 * (k3 >> 3)) & 31);
        wsrc0 = W + (size_t)(kbase + k0) * DH + n0 + (c0 << 2);
        wsrc1 = W + (size_t)(kbase + k1) * DH + n0 + (c1 << 2);
        wsrc2 = W + (size_t)(kbase + k2) * DH + n0 + (c2 << 2);
        wsrc3 = W + (size_t)(kbase + k3) * DH + n0 + (c3 << 2);
    }
    // packed A: stage t = 16 KB contiguous (both m-halves) at ap + t*16384
    const char* ap = Ap + (size_t)(y * (Kh >> 5) * 2) * 8192;

    auto issue = [&](int slot) {      // 8 DMA instr/thread; advance 1 stage
        char* dst = &lds[slot][0];
        gload16(wsrc0, dst + (size_t)tid * 16);          wsrc0 += 32 * DH;
        gload16(wsrc1, dst + (size_t)(tid + 256) * 16);  wsrc1 += 32 * DH;
        gload16(wsrc2, dst + (size_t)(tid + 512) * 16);  wsrc2 += 32 * DH;
        gload16(wsrc3, dst + (size_t)(tid + 768) * 16);  wsrc3 += 32 * DH;
        gload16(ap + (size_t)tid * 16,         dst + 16384 + (size_t)tid * 16);
        gload16(ap + (size_t)tid * 16 + 4096,  dst + 16384 + (size_t)tid * 16 + 4096);
        gload16(ap + (size_t)tid * 16 + 8192,  dst + 16384 + (size_t)tid * 16 + 8192);
        gload16(ap + (size_t)tid * 16 + 12288, dst + 16384 + (size_t)tid * 16 + 12288);
        ap += 16384;
    };

    const int q  = lane >> 4;
    const int lc = lane & 15;
    auto step = [&](int slot) {
        const float* wl = (const float*)&lds[slot][0];
        const f16*   al = (const f16*)&lds[slot][16384];
        f16x8 af[8], bf[4];
#pragma unroll
        for (int ri8 = 0; ri8 < 8; ++ri8) {
            // packed: mhalf=wm, h = ((ri8>>2)<<8)|((ri8&3)<<6)|(q<<4)|lc = base+lane
            int off = (wm << 12) + (((ri8 >> 2) << 8) | ((ri8 & 3) << 6)) + lane;
            af[ri8] = *(const f16x8*)(al + ((size_t)off << 3));
        }
        const int wbase = (q << 10) + (lc & 3);
#pragma unroll
        for (int ni = 0; ni < 4; ++ni) {
            int p = ((wn << 4) + (ni << 2) + (lc >> 2)) ^ (5 * q);
            int fi = wbase + ((p & 31) << 2);
            f16x8 b;
#pragma unroll
            for (int j = 0; j < 8; ++j)
                b[j] = (_Float16)wl[fi + (j << 7)];
            bf[ni] = b;
        }
#pragma unroll
        for (int ri = 0; ri < 8; ++ri)
#pragma unroll
            for (int ni = 0; ni < 4; ++ni)
                acc[ri][ni] = __builtin_amdgcn_mfma_f32_16x16x32_f16(
                    af[ri], bf[ni], acc[ri][ni], 0, 0, 0);
    };

    issue(0);
    issue(1);
    __builtin_amdgcn_sched_barrier(0);

    for (int t = 0; t < ns; ++t) {
        if (t + 1 < ns) asm volatile("s_waitcnt vmcnt(8)" ::: "memory");
        else            asm volatile("s_waitcnt vmcnt(0)" ::: "memory");
        __builtin_amdgcn_sched_barrier(0);
        __builtin_amdgcn_s_barrier();
        __builtin_amdgcn_sched_barrier(0);
        step(t & 1);
        __builtin_amdgcn_sched_barrier(0);
        asm volatile("s_waitcnt lgkmcnt(0)" ::: "memory");
        __builtin_amdgcn_sched_barrier(0);
        __builtin_amdgcn_s_barrier();
        __builtin_amdgcn_sched_barrier(0);
        if (t + 2 < ns) {
            issue(t & 1);
            __builtin_amdgcn_sched_barrier(0);
        }
    }

    // epilogue: D layout col=lane&15, row=(lane>>4)*4+reg  [m89-verified]
    f16* Pb = P + (size_t)y * (256 * DH);
#pragma unroll
    for (int ri = 0; ri < 8; ++ri) {
        int row = wm * 128 + ri * 16 + (q << 2);
#pragma unroll
        for (int ni = 0; ni < 4; ++ni) {
            int col = n0 + wn * 64 + ni * 16 + lc;
#pragma unroll
            for (int rg = 0; rg < 4; ++rg)
                Pb[(size_t)(row + rg) * DH + col] = (_Float16)acc[ri][ni][rg];
        }
    }
}

// ---------------- splitK reduce (f16 partials) + bias + relu ----------------
// ohp != null: write PACKED granules (pk_off layout)
__global__ __launch_bounds__(256) void reduce_kernel(
    const f16* __restrict__ P, int S,
    const float* __restrict__ bias,
    char* __restrict__ ohp, float* __restrict__ out32) {
    const size_t n = 256 * DH;
    const size_t i = ((size_t)blockIdx.x * 256 + threadIdx.x) * 8;
    if (i >= n) return;
    const int row = (int)(i / DH);
    const int d   = (int)(i % DH);
    float r[8];
    {
        float4 b0 = *(const float4*)(bias + d);
        float4 b1 = *(const float4*)(bias + d + 4);
        r[0] = b0.x; r[1] = b0.y; r[2] = b0.z; r[3] = b0.w;
        r[4] = b1.x; r[5] = b1.y; r[6] = b1.z; r[7] = b1.w;
    }
    for (int j = 0; j < S; ++j) {
        f16x8 v = *(const f16x8*)(P + (size_t)j * n + i);
#pragma unroll
        for (int e = 0; e < 8; ++e) r[e] += (float)v[e];
    }
#pragma unroll
    for (int e = 0; e < 8; ++e) r[e] = fmaxf(r[e], 0.f);
    if (ohp) {
        f16x8 h;
#pragma unroll
        for (int e = 0; e < 8; ++e) h[e] = (_Float16)r[e];
        *(f16x8*)(ohp + pk_off(row, d)) = h;
    }
    if (out32) {
        float4 o0 = {r[0], r[1], r[2], r[3]};
        float4 o1 = {r[4], r[5], r[6], r[7]};
        *(float4*)(out32 + i) = o0;
        *(float4*)(out32 + i + 4) = o1;
    }
}

// ---------------- action head: softmax(X3[:, :8960] @ Wa + ba) --------------
__global__ __launch_bounds__(256) void action_kernel(
    const float* __restrict__ X3, const float* __restrict__ Wa,
    const float* __restrict__ ba, float* __restrict__ xact) {
    __shared__ float xs[SPLIT];
    __shared__ float red[256];
    const int row = blockIdx.x, t = threadIdx.x;
    const float* xr = X3 + (size_t)row * DH;
    for (int k = t * 4; k < SPLIT; k += 1024)
        *(float4*)&xs[k] = *(const float4*)(xr + k);
    __syncthreads();
    const int col = t & 63, kqq = t >> 6;
    float acc = 0.f;
    for (int k = kqq * 2240; k < (kqq + 1) * 2240; ++k)
        acc += xs[k] * Wa[(size_t)k * 64 + col];
    red[t] = acc;
    __syncthreads();
    if (t < 64) {
        float z = red[t] + red[t + 64] + red[t + 128] + red[t + 192] + ba[t];
        float mx = z;
        for (int off = 32; off; off >>= 1) mx = fmaxf(mx, __shfl_xor(mx, off));
        float e = expf(z - mx);
        float s = e;
        for (int off = 32; off; off >>= 1) s += __shfl_xor(s, off);
        xact[row * 64 + t] = e / s;
    }
}

// ---------------- selection head + final outputs ---------------------------
__global__ __launch_bounds__(256) void select_kernel(
    const float* __restrict__ X3, const float* __restrict__ Ws,
    const float* __restrict__ bs, const void* __restrict__ maskp,
    const float* __restrict__ u, const float* __restrict__ xact,
    float* __restrict__ out) {
    __shared__ float xs[256];
    __shared__ float psh[256];
    __shared__ float rr[4];
    __shared__ float bestv[4];
    __shared__ int besti[4];
    __shared__ int sIdx;
    __shared__ int smode;
    const int row = blockIdx.x, t = threadIdx.x;
    const int lane = t & 63, wid = t >> 6;

    // mask dtype detection: int32 {0,1} / bytes {0,1} / float {0.f,1.f}
    if (t < 64) {
        unsigned v = ((const unsigned*)maskp)[t];
        int okInt  = __all(v <= 1u);
        int okByte = __all((v & 0xFEFEFEFEu) == 0u);
        if (t == 0) smode = okInt ? 0 : (okByte ? 1 : 2);
    }
    xs[t] = X3[(size_t)row * DH + SPLIT + t];
    __syncthreads();

    bool mk;
    if (smode == 0)       mk = ((const int*)maskp)[row * 256 + t] != 0;
    else if (smode == 1)  mk = ((const unsigned char*)maskp)[row * 256 + t] != 0;
    else                  mk = ((const float*)maskp)[row * 256 + t] != 0.0f;

    float z = bs[t];
    for (int k = 0; k < 256; ++k)
        z += xs[k] * Ws[k * 256 + t];

    // softmax #1
    float v = z;
    for (int off = 32; off; off >>= 1) v = fmaxf(v, __shfl_xor(v, off));
    if (lane == 0) rr[wid] = v;
    __syncthreads();
    float m1 = fmaxf(fmaxf(rr[0], rr[1]), fmaxf(rr[2], rr[3]));
    __syncthreads();
    float e1 = expf(z - m1);
    v = e1;
    for (int off = 32; off; off >>= 1) v += __shfl_xor(v, off);
    if (lane == 0) rr[wid] = v;
    __syncthreads();
    float s1 = rr[0] + rr[1] + rr[2] + rr[3];
    __syncthreads();
    float p1 = e1 / s1;

    // mask, softmax #2
    float q = mk ? -1e9f : p1;
    v = q;
    for (int off = 32; off; off >>= 1) v = fmaxf(v, __shfl_xor(v, off));
    if (lane == 0) rr[wid] = v;
    __syncthreads();
    float m2 = fmaxf(fmaxf(rr[0], rr[1]), fmaxf(rr[2], rr[3]));
    __syncthreads();
    float e2 = expf(q - m2);
    v = e2;
    for (int off = 32; off; off >>= 1) v += __shfl_xor(v, off);
    if (lane == 0) rr[wid] = v;
    __syncthreads();
    float s2 = rr[0] + rr[1] + rr[2] + rr[3];
    float p2 = e2 / s2;
    psh[t] = p2;

    // gumbel scores + first-occurrence argmax
    float g = -logf(-logf(u[row * 256 + t]));
    float sc = mk ? -INFINITY : (logf(p2) + g);
    float bv = sc;
    int bi = t;
    for (int off = 32; off; off >>= 1) {
        float ov = __shfl_xor(bv, off);
        int oi = __shfl_xor(bi, off);
        if (ov > bv || (ov == bv && oi < bi)) { bv = ov; bi = oi; }
    }
    if (lane == 0) { bestv[wid] = bv; besti[wid] = bi; }
    __syncthreads();
    if (t == 0) {
        float fv = bestv[0];
        int fi = besti[0];
        for (int w = 1; w < 4; ++w)
            if (bestv[w] > fv || (bestv[w] == fv && besti[w] < fi)) {
                fv = bestv[w]; fi = besti[w];
            }
        sIdx = fi;
    }
    __syncthreads();
    const int idx = sIdx;
    const float sp = psh[idx];
    if (t < 64) out[row * 64 + t] = xact[row * 64 + t] * sp;
    if (t == 0) {
        out[256 * 64 + row * 2 + 0] = (float)(idx >> 4);
        out[256 * 64 + row * 2 + 1] = (float)(idx & 15);
    }
}

// ---------------------------------------------------------------------------
extern "C" void kernel_launch(void* const* d_in, const int* in_sizes, int n_in,
                              void* d_out, int out_size, void* d_ws, size_t ws_size,
                              hipStream_t stream) {
    const float* s  = (const float*)d_in[0];
    const void*  mask = d_in[1];
    const float* u  = (const float*)d_in[2];
    const float* W1 = (const float*)d_in[3];
    const float* b1 = (const float*)d_in[4];
    const float* W2 = (const float*)d_in[5];
    const float* b2 = (const float*)d_in[6];
    const float* W3 = (const float*)d_in[7];
    const float* b3 = (const float*)d_in[8];
    const float* Wa = (const float*)d_in[9];
    const float* ba = (const float*)d_in[10];
    const float* Ws = (const float*)d_in[11];
    const float* bs = (const float*)d_in[12];
    float* out = (float*)d_out;
    char* ws = (char*)d_ws;

    // workspace map:
    //   [0,        8,388,608)  A0p packed f16 (K=16384)   (reused by X2p)
    //   [8388608, 13,107,200)  X1p packed f16 (K=9216)
    //   [13107200,22,544,384)  X3 f32 [256][9216]
    //   [22544384,22,609,920)  XA f32 [256][64]
    //   [22609920, ...)        P  f16 [S][256][9216]  (4.72 MB/plane)
    char*  A0p = ws + 0;
    char*  X1p = ws + 8388608;
    char*  X2p = ws + 0;                   // reuses dead A0p
    float* X3  = (float*)(ws + 13107200);
    float* XA  = (float*)(ws + 22544384);
    f16*   P   = (f16*)(ws + 22609920);

    const size_t pbytes = 4718592ull;      // one f16 splitK plane
    int yshift = (ws_size >= 22609920ull + 8 * pbytes) ? 3 : 2;
    const int S = 1 << yshift;

    cvt_kernel<<<2048, 256, 0, stream>>>(s, A0p);

    const int nblk = 72 << yshift;         // 576 @ S=8; y = bid & (S-1)
    gemm_kernel<<<nblk, 256, 0, stream>>>(A0p, 16384, 16384 / S, yshift, W1, P);
    reduce_kernel<<<1152, 256, 0, stream>>>(P, S, b1, X1p, nullptr);
    gemm_kernel<<<nblk, 256, 0, stream>>>(X1p, DH, DH / S, yshift, W2, P);
    reduce_kernel<<<1152, 256, 0, stream>>>(P, S, b2, X2p, nullptr);
    gemm_kernel<<<nblk, 256, 0, stream>>>(X2p, DH, DH / S, yshift, W3, P);
    reduce_kernel<<<1152, 256, 0, stream>>>(P, S, b3, nullptr, X3);

    action_kernel<<<256, 256, 0, stream>>>(X3, Wa, ba, XA);
    select_kernel<<<256, 256, 0, stream>>>(X3, Ws, bs, mask, u, XA, out);
}